// Round 2
// baseline (899.418 us; speedup 1.0000x reference)
//
#include <hip/hip_runtime.h>

#define IN_F 128
#define OUT_F 64
#define NEG_SLOPE 0.2f

// ---------------- Pass 1: tiled GEMM  Wh = x@W, fused el/er projections ----
// 64 rows x 64 cols per block, K=128 staged in LDS, 4x4 register blocking.
__global__ void __launch_bounds__(256) gemm_tiled(
    const float* __restrict__ x, const float* __restrict__ W,
    const float* __restrict__ a_l, const float* __restrict__ a_r,
    float* __restrict__ Wh, float* __restrict__ el, float* __restrict__ er,
    int N)
{
    __shared__ float xs[64][140];   // pad 140: 140*4=560=35*16 keeps f4 align; banks 2-way (free)
    __shared__ float Ws[128][64];   // reads Ws[k][4tx] b128: 2-way (free)

    const int t = threadIdx.x;
    const int row0 = blockIdx.x * 64;

    // load W (8192 floats) via float4
    {
        const float4* Wsrc = (const float4*)W;
        float4* Wd = (float4*)(&Ws[0][0]);
#pragma unroll
        for (int i = 0; i < 8; ++i) Wd[t + 256 * i] = Wsrc[t + 256 * i];
    }
    // load x tile (64 rows x 128 cols) via float4, coalesced
    {
        int r = t >> 5;           // 0..7
        int c = (t & 31) * 4;     // 0..124
#pragma unroll
        for (int i = 0; i < 8; ++i) {
            int rr = r + 8 * i;
            int grow = row0 + rr;
            float4 v = make_float4(0.f, 0.f, 0.f, 0.f);
            if (grow < N) v = *(const float4*)(x + (size_t)grow * IN_F + c);
            xs[rr][c] = v.x; xs[rr][c + 1] = v.y; xs[rr][c + 2] = v.z; xs[rr][c + 3] = v.w;
        }
    }
    __syncthreads();

    const int tx = t & 15, ty = t >> 4;   // lane = (ty&3)*16 + tx
    float acc[4][4] = {};

#pragma unroll
    for (int kk = 0; kk < 32; ++kk) {
        float xr[4][4], wr[4][4];
#pragma unroll
        for (int i = 0; i < 4; ++i) {
            float4 v = *(const float4*)&xs[4 * ty + i][4 * kk];
            xr[i][0] = v.x; xr[i][1] = v.y; xr[i][2] = v.z; xr[i][3] = v.w;
        }
#pragma unroll
        for (int kc = 0; kc < 4; ++kc) {
            float4 v = *(const float4*)&Ws[4 * kk + kc][4 * tx];
            wr[kc][0] = v.x; wr[kc][1] = v.y; wr[kc][2] = v.z; wr[kc][3] = v.w;
        }
#pragma unroll
        for (int kc = 0; kc < 4; ++kc)
#pragma unroll
            for (int i = 0; i < 4; ++i)
#pragma unroll
                for (int j = 0; j < 4; ++j)
                    acc[i][j] = fmaf(xr[i][kc], wr[kc][j], acc[i][j]);
    }

    // epilogue: store Wh, fused el/er row-dots with 16-lane shfl reduce
    float4 al4 = ((const float4*)a_l)[tx];
    float4 ar4 = ((const float4*)a_r)[tx];
    float alv[4] = {al4.x, al4.y, al4.z, al4.w};
    float arv[4] = {ar4.x, ar4.y, ar4.z, ar4.w};

#pragma unroll
    for (int i = 0; i < 4; ++i) {
        int grow = row0 + 4 * ty + i;
        if (grow < N) {
            float4 o = make_float4(acc[i][0], acc[i][1], acc[i][2], acc[i][3]);
            *(float4*)(Wh + (size_t)grow * OUT_F + 4 * tx) = o;
        }
        float pl = acc[i][0] * alv[0] + acc[i][1] * alv[1] + acc[i][2] * alv[2] + acc[i][3] * alv[3];
        float pr = acc[i][0] * arv[0] + acc[i][1] * arv[1] + acc[i][2] * arv[2] + acc[i][3] * arv[3];
#pragma unroll
        for (int off = 1; off < 16; off <<= 1) {   // reduce across tx (bits 0..3 of lane)
            pl += __shfl_xor(pl, off);
            pr += __shfl_xor(pr, off);
        }
        if (tx == 0 && grow < N) { el[grow] = pl; er[grow] = pr; }
    }
}

// ---------------- CSR build: histogram -> scan -> bin ----------------------
__global__ void __launch_bounds__(256) hist_k(
    const int* __restrict__ src, int* __restrict__ hist, int E)
{
    int e = blockIdx.x * blockDim.x + threadIdx.x;
    if (e < E) atomicAdd(&hist[src[e]], 1);
}

// block-scan of 1024 ints; writes partial exclusive scan + block sums
__global__ void __launch_bounds__(1024) scan_a(
    const int* __restrict__ in, int* __restrict__ part, int* __restrict__ bsum, int n)
{
    __shared__ int wsum[16];
    const int t = threadIdx.x, b = blockIdx.x;
    const int i = b * 1024 + t;
    const int lane = t & 63, wid = t >> 6;
    int v = (i < n) ? in[i] : 0;
    int incl = v;
#pragma unroll
    for (int off = 1; off < 64; off <<= 1) {
        int o = __shfl_up(incl, off);
        if (lane >= off) incl += o;
    }
    if (lane == 63) wsum[wid] = incl;
    __syncthreads();
    if (wid == 0) {
        int s = (lane < 16) ? wsum[lane] : 0;
#pragma unroll
        for (int off = 1; off < 16; off <<= 1) {
            int o = __shfl_up(s, off);
            if (lane >= off) s += o;
        }
        if (lane < 16) wsum[lane] = s;   // inclusive wave totals
    }
    __syncthreads();
    int base = (wid > 0) ? wsum[wid - 1] : 0;
    if (i < n) part[i] = base + incl - v;
    if (t == 1023) bsum[b] = wsum[15];
}

// scan of <=128 block sums, single block
__global__ void __launch_bounds__(128) scan_b(
    const int* __restrict__ bsum, int* __restrict__ boff, int nb)
{
    __shared__ int w0tot;
    const int t = threadIdx.x, lane = t & 63, wid = t >> 6;
    int v = (t < nb) ? bsum[t] : 0;
    int incl = v;
#pragma unroll
    for (int off = 1; off < 64; off <<= 1) {
        int o = __shfl_up(incl, off);
        if (lane >= off) incl += o;
    }
    if (wid == 0 && lane == 63) w0tot = incl;
    __syncthreads();
    int excl = incl - v + (wid == 1 ? w0tot : 0);
    if (t < nb) boff[t] = excl;
}

// add block offsets; also init cursor = row_ptr
__global__ void __launch_bounds__(256) scan_c(
    int* __restrict__ part, const int* __restrict__ boff, int* __restrict__ cursor, int n)
{
    int i = blockIdx.x * blockDim.x + threadIdx.x;
    if (i < n) {
        int rp = part[i] + boff[i >> 10];
        part[i] = rp;
        if (i < n - 1) cursor[i] = rp;
    }
}

__global__ void __launch_bounds__(256) bin_k(
    const int* __restrict__ src, const int* __restrict__ dst,
    int* __restrict__ cursor, int* __restrict__ sdst, int E)
{
    int e = blockIdx.x * blockDim.x + threadIdx.x;
    if (e < E) {
        int s = src[e];
        int pos = atomicAdd(&cursor[s], 1);
        sdst[pos] = dst[e];
    }
}

// ---------------- node kernel: softmax + gather-aggregate + relu ----------
// one wave per node; lane = output column
__global__ void __launch_bounds__(256) node_k(
    const int* __restrict__ row_ptr, const int* __restrict__ sdst,
    const float* __restrict__ el, const float* __restrict__ er,
    const float* __restrict__ Wh, float* __restrict__ out, int N)
{
    const int lane = threadIdx.x & 63;
    const int node = (blockIdx.x * blockDim.x + threadIdx.x) >> 6;
    if (node >= N) return;

    const int start = row_ptr[node], end = row_ptr[node + 1];
    const float elc = el[node];

    // phase A: segment max
    float m = -1e30f;
    for (int base = start; base < end; base += 64) {
        int idx = base + lane;
        if (idx < end) {
            int d = sdst[idx];
            float v = elc + er[d];
            v = v > 0.f ? v : NEG_SLOPE * v;
            m = fmaxf(m, v);
        }
    }
#pragma unroll
    for (int off = 32; off; off >>= 1) m = fmaxf(m, __shfl_xor(m, off));

    // phase B: exp + sum + message accumulation
    float Z = 0.f, acc = 0.f;
    for (int base = start; base < end; base += 64) {
        int idx = base + lane;
        int cnt = min(64, end - base);
        float p = 0.f;
        int d = 0;
        if (idx < end) {
            d = sdst[idx];
            float v = elc + er[d];
            v = v > 0.f ? v : NEG_SLOPE * v;
            p = __expf(v - m);
        }
        Z += p;
        for (int j = 0; j < cnt; ++j) {
            int dj = __shfl(d, j);
            float pj = __shfl(p, j);
            acc = fmaf(pj, Wh[(size_t)dj * OUT_F + lane], acc);
        }
    }
#pragma unroll
    for (int off = 32; off; off >>= 1) Z += __shfl_xor(Z, off);

    out[(size_t)node * OUT_F + lane] = fmaxf(acc / (Z + 1e-9f), 0.f);
}

// ---------------------------------------------------------------------------
extern "C" void kernel_launch(void* const* d_in, const int* in_sizes, int n_in,
                              void* d_out, int out_size, void* d_ws, size_t ws_size,
                              hipStream_t stream)
{
    const float* x   = (const float*)d_in[0];
    const float* W   = (const float*)d_in[1];
    const float* a_l = (const float*)d_in[2];
    const float* a_r = (const float*)d_in[3];
    const int*   ei  = (const int*)d_in[4];

    const int N = in_sizes[0] / IN_F;
    const int E = in_sizes[4] / 2;
    const int* src = ei;
    const int* dst = ei + E;
    float* out = (float*)d_out;

    // workspace carve-up (256B-aligned)
    auto align = [](size_t v) { return (v + 255) & ~(size_t)255; };
    char* ws = (char*)d_ws;
    size_t off = 0;
    float* Wh      = (float*)(ws + off); off = align(off + (size_t)N * OUT_F * 4);
    float* el      = (float*)(ws + off); off = align(off + (size_t)N * 4);
    float* er      = (float*)(ws + off); off = align(off + (size_t)N * 4);
    int*   hist    = (int*)(ws + off);   off = align(off + (size_t)(N + 1) * 4);  // reused as cursor
    int*   row_ptr = (int*)(ws + off);   off = align(off + (size_t)(N + 1) * 4);
    int*   sdst    = (int*)(ws + off);   off = align(off + (size_t)E * 4);
    int*   bsum    = (int*)(ws + off);   off = align(off + 1024);
    int*   boff    = (int*)(ws + off);   off = align(off + 1024);

    const int n_scan = N + 1;
    const int nb = (n_scan + 1023) / 1024;

    hipMemsetAsync(hist, 0, (size_t)(N + 1) * 4, stream);

    gemm_tiled<<<(N + 63) / 64, 256, 0, stream>>>(x, W, a_l, a_r, Wh, el, er, N);

    hist_k<<<(E + 255) / 256, 256, 0, stream>>>(src, hist, E);
    scan_a<<<nb, 1024, 0, stream>>>(hist, row_ptr, bsum, n_scan);
    scan_b<<<1, 128, 0, stream>>>(bsum, boff, nb);
    scan_c<<<(n_scan + 255) / 256, 256, 0, stream>>>(row_ptr, boff, hist /*cursor*/, n_scan);
    bin_k<<<(E + 255) / 256, 256, 0, stream>>>(src, dst, hist /*cursor*/, sdst, E);

    node_k<<<(N * 64 + 255) / 256, 256, 0, stream>>>(row_ptr, sdst, el, er, Wh, out, N);
}

// Round 4
// 433.545 us; speedup vs baseline: 2.0746x; 2.0746x over previous
//
#include <hip/hip_runtime.h>

#define IN_F 128
#define OUT_F 64
#define NEG_SLOPE 0.2f

__device__ __forceinline__ unsigned short f2bf(float f) {   // round-nearest-even
    unsigned u = __float_as_uint(f);
    unsigned r = (u + 0x7FFFu + ((u >> 16) & 1u)) >> 16;
    return (unsigned short)r;
}
__device__ __forceinline__ float bf2f(unsigned short b) {
    return __uint_as_float(((unsigned)b) << 16);
}

// ---------------- Pass 1: tiled GEMM  Wh(bf16) = x@W, fused el/er ----------
// 64 rows x 64 cols per block, K=128 in LDS, 4x4 register blocking.
// VGPR discipline: only acc[16] + xv[16] + wv[4] live; unroll capped at 2.
__global__ void __launch_bounds__(256) gemm_tiled(
    const float* __restrict__ x, const float* __restrict__ W,
    const float* __restrict__ a_l, const float* __restrict__ a_r,
    unsigned short* __restrict__ Whb, float* __restrict__ el, float* __restrict__ er,
    int N)
{
    __shared__ float xs[64][132];   // 132: f4-aligned rows; reads are broadcast + 2-way (free)
    __shared__ float Ws[128][64];

    const int t = threadIdx.x;
    const int row0 = blockIdx.x * 64;

    {   // load W (8192 floats) via float4
        const float4* Wsrc = (const float4*)W;
        float4* Wd = (float4*)(&Ws[0][0]);
#pragma unroll
        for (int i = 0; i < 8; ++i) Wd[t + 256 * i] = Wsrc[t + 256 * i];
    }
    {   // load x tile (64x128) via float4, coalesced
        int r = t >> 5;
        int c = (t & 31) * 4;
#pragma unroll
        for (int i = 0; i < 8; ++i) {
            int rr = r + 8 * i;
            int grow = row0 + rr;
            float4 v = make_float4(0.f, 0.f, 0.f, 0.f);
            if (grow < N) v = *(const float4*)(x + (size_t)grow * IN_F + c);
            xs[rr][c] = v.x; xs[rr][c + 1] = v.y; xs[rr][c + 2] = v.z; xs[rr][c + 3] = v.w;
        }
    }
    __syncthreads();

    const int tx = t & 15, ty = t >> 4;
    float acc[4][4] = {};

#pragma unroll 2
    for (int kk = 0; kk < 32; ++kk) {
        float4 xv[4];
#pragma unroll
        for (int i = 0; i < 4; ++i) xv[i] = *(const float4*)&xs[4 * ty + i][4 * kk];
#pragma unroll
        for (int kc = 0; kc < 4; ++kc) {
            float4 wv = *(const float4*)&Ws[4 * kk + kc][4 * tx];
#pragma unroll
            for (int i = 0; i < 4; ++i) {
                float xe = (kc == 0) ? xv[i].x : (kc == 1) ? xv[i].y : (kc == 2) ? xv[i].z : xv[i].w;
                acc[i][0] = fmaf(xe, wv.x, acc[i][0]);
                acc[i][1] = fmaf(xe, wv.y, acc[i][1]);
                acc[i][2] = fmaf(xe, wv.z, acc[i][2]);
                acc[i][3] = fmaf(xe, wv.w, acc[i][3]);
            }
        }
    }

    // epilogue: bf16 Wh store + fused el/er row-dots (16-lane shfl reduce)
    float4 al4 = ((const float4*)a_l)[tx];
    float4 ar4 = ((const float4*)a_r)[tx];

#pragma unroll
    for (int i = 0; i < 4; ++i) {
        int grow = row0 + 4 * ty + i;
        if (grow < N) {
            ushort4 o;
            o.x = f2bf(acc[i][0]); o.y = f2bf(acc[i][1]);
            o.z = f2bf(acc[i][2]); o.w = f2bf(acc[i][3]);
            *(ushort4*)(Whb + (size_t)grow * OUT_F + 4 * tx) = o;
        }
        float pl = acc[i][0] * al4.x + acc[i][1] * al4.y + acc[i][2] * al4.z + acc[i][3] * al4.w;
        float pr = acc[i][0] * ar4.x + acc[i][1] * ar4.y + acc[i][2] * ar4.z + acc[i][3] * ar4.w;
#pragma unroll
        for (int off = 1; off < 16; off <<= 1) {
            pl += __shfl_xor(pl, off);
            pr += __shfl_xor(pr, off);
        }
        if (tx == 0 && grow < N) { el[grow] = pl; er[grow] = pr; }
    }
}

// ---------------- CSR build: histogram -> scan -> bin ----------------------
__global__ void __launch_bounds__(256) hist_k(
    const int* __restrict__ src, int* __restrict__ hist, int E)
{
    int e = blockIdx.x * blockDim.x + threadIdx.x;
    if (e < E) atomicAdd(&hist[src[e]], 1);
}

__global__ void __launch_bounds__(1024) scan_a(
    const int* __restrict__ in, int* __restrict__ part, int* __restrict__ bsum, int n)
{
    __shared__ int wsum[16];
    const int t = threadIdx.x, b = blockIdx.x;
    const int i = b * 1024 + t;
    const int lane = t & 63, wid = t >> 6;
    int v = (i < n) ? in[i] : 0;
    int incl = v;
#pragma unroll
    for (int off = 1; off < 64; off <<= 1) {
        int o = __shfl_up(incl, off);
        if (lane >= off) incl += o;
    }
    if (lane == 63) wsum[wid] = incl;
    __syncthreads();
    if (wid == 0) {
        int s = (lane < 16) ? wsum[lane] : 0;
#pragma unroll
        for (int off = 1; off < 16; off <<= 1) {
            int o = __shfl_up(s, off);
            if (lane >= off) s += o;
        }
        if (lane < 16) wsum[lane] = s;
    }
    __syncthreads();
    int base = (wid > 0) ? wsum[wid - 1] : 0;
    if (i < n) part[i] = base + incl - v;
    if (t == 1023) bsum[b] = wsum[15];
}

__global__ void __launch_bounds__(128) scan_b(
    const int* __restrict__ bsum, int* __restrict__ boff, int nb)
{
    __shared__ int w0tot;
    const int t = threadIdx.x, lane = t & 63, wid = t >> 6;
    int v = (t < nb) ? bsum[t] : 0;
    int incl = v;
#pragma unroll
    for (int off = 1; off < 64; off <<= 1) {
        int o = __shfl_up(incl, off);
        if (lane >= off) incl += o;
    }
    if (wid == 0 && lane == 63) w0tot = incl;
    __syncthreads();
    int excl = incl - v + (wid == 1 ? w0tot : 0);
    if (t < nb) boff[t] = excl;
}

__global__ void __launch_bounds__(256) scan_c(
    int* __restrict__ part, const int* __restrict__ boff, int* __restrict__ cursor, int n)
{
    int i = blockIdx.x * blockDim.x + threadIdx.x;
    if (i < n) {
        int rp = part[i] + boff[i >> 10];
        part[i] = rp;
        if (i < n - 1) cursor[i] = rp;
    }
}

__global__ void __launch_bounds__(256) bin_k(
    const int* __restrict__ src, const int* __restrict__ dst,
    int* __restrict__ cursor, int* __restrict__ sdst, int E)
{
    int e = blockIdx.x * blockDim.x + threadIdx.x;
    if (e < E) {
        int s = src[e];
        int pos = atomicAdd(&cursor[s], 1);
        sdst[pos] = dst[e];
    }
}

// ---------------- node kernel: softmax + bf16 gather-aggregate + relu ------
// one wave per node; lane = output column
__global__ void __launch_bounds__(256) node_k(
    const int* __restrict__ row_ptr, const int* __restrict__ sdst,
    const float* __restrict__ el, const float* __restrict__ er,
    const unsigned short* __restrict__ Whb, float* __restrict__ out, int N)
{
    const int lane = threadIdx.x & 63;
    const int node = (blockIdx.x * blockDim.x + threadIdx.x) >> 6;
    if (node >= N) return;

    const int start = row_ptr[node], end = row_ptr[node + 1];
    const float elc = el[node];

    float m = -1e30f;
    for (int base = start; base < end; base += 64) {
        int idx = base + lane;
        if (idx < end) {
            int d = sdst[idx];
            float v = elc + er[d];
            v = v > 0.f ? v : NEG_SLOPE * v;
            m = fmaxf(m, v);
        }
    }
#pragma unroll
    for (int off = 32; off; off >>= 1) m = fmaxf(m, __shfl_xor(m, off));

    float Z = 0.f, acc = 0.f;
    for (int base = start; base < end; base += 64) {
        int idx = base + lane;
        int cnt = min(64, end - base);
        float p = 0.f;
        int d = 0;
        if (idx < end) {
            d = sdst[idx];
            float v = elc + er[d];
            v = v > 0.f ? v : NEG_SLOPE * v;
            p = __expf(v - m);
        }
        Z += p;
        for (int j = 0; j < cnt; ++j) {
            int dj = __shfl(d, j);
            float pj = __shfl(p, j);
            acc = fmaf(pj, bf2f(Whb[(size_t)dj * OUT_F + lane]), acc);
        }
    }
#pragma unroll
    for (int off = 32; off; off >>= 1) Z += __shfl_xor(Z, off);

    out[(size_t)node * OUT_F + lane] = fmaxf(acc / (Z + 1e-9f), 0.f);
}

// ---------------------------------------------------------------------------
extern "C" void kernel_launch(void* const* d_in, const int* in_sizes, int n_in,
                              void* d_out, int out_size, void* d_ws, size_t ws_size,
                              hipStream_t stream)
{
    const float* x   = (const float*)d_in[0];
    const float* W   = (const float*)d_in[1];
    const float* a_l = (const float*)d_in[2];
    const float* a_r = (const float*)d_in[3];
    const int*   ei  = (const int*)d_in[4];

    const int N = in_sizes[0] / IN_F;
    const int E = in_sizes[4] / 2;
    const int* src = ei;
    const int* dst = ei + E;
    float* out = (float*)d_out;

    auto align = [](size_t v) { return (v + 255) & ~(size_t)255; };
    char* ws = (char*)d_ws;
    size_t off = 0;
    unsigned short* Whb = (unsigned short*)(ws + off); off = align(off + (size_t)N * OUT_F * 2);
    float* el      = (float*)(ws + off); off = align(off + (size_t)N * 4);
    float* er      = (float*)(ws + off); off = align(off + (size_t)N * 4);
    int*   hist    = (int*)(ws + off);   off = align(off + (size_t)(N + 1) * 4);  // reused as cursor
    int*   row_ptr = (int*)(ws + off);   off = align(off + (size_t)(N + 1) * 4);
    int*   sdst    = (int*)(ws + off);   off = align(off + (size_t)E * 4);
    int*   bsum    = (int*)(ws + off);   off = align(off + 1024);
    int*   boff    = (int*)(ws + off);   off = align(off + 1024);

    const int n_scan = N + 1;
    const int nb = (n_scan + 1023) / 1024;

    hipMemsetAsync(hist, 0, (size_t)(N + 1) * 4, stream);

    gemm_tiled<<<(N + 63) / 64, 256, 0, stream>>>(x, W, a_l, a_r, Whb, el, er, N);

    hist_k<<<(E + 255) / 256, 256, 0, stream>>>(src, hist, E);
    scan_a<<<nb, 1024, 0, stream>>>(hist, row_ptr, bsum, n_scan);
    scan_b<<<1, 128, 0, stream>>>(bsum, boff, nb);
    scan_c<<<(n_scan + 255) / 256, 256, 0, stream>>>(row_ptr, boff, hist, n_scan);
    bin_k<<<(E + 255) / 256, 256, 0, stream>>>(src, dst, hist, sdst, E);

    node_k<<<(N * 64 + 255) / 256, 256, 0, stream>>>(row_ptr, sdst, el, er, Whb, out, N);
}

// Round 7
// 314.104 us; speedup vs baseline: 2.8634x; 1.3803x over previous
//
#include <hip/hip_runtime.h>

#define IN_F 128
#define OUT_F 64
#define NEG_SLOPE 0.2f
#define NBLK 256          // blocks for countA/binB
#define LCAP 4096         // max bucket records staged in LDS

__device__ __forceinline__ unsigned short f2bf(float f) {   // round-nearest-even
    unsigned u = __float_as_uint(f);
    unsigned r = (u + 0x7FFFu + ((u >> 16) & 1u)) >> 16;
    return (unsigned short)r;
}
__device__ __forceinline__ float bf2f(unsigned short b) {
    return __uint_as_float(((unsigned)b) << 16);
}

// ---------------- Pass 1: tiled GEMM  Wh(bf16) = x@W, fused el/er ----------
__global__ void __launch_bounds__(256) gemm_tiled(
    const float* __restrict__ x, const float* __restrict__ W,
    const float* __restrict__ a_l, const float* __restrict__ a_r,
    unsigned short* __restrict__ Whb, float* __restrict__ el, float* __restrict__ er,
    int N)
{
    __shared__ float xs[64][132];
    __shared__ float Ws[128][64];

    const int t = threadIdx.x;
    const int row0 = blockIdx.x * 64;

    {
        const float4* Wsrc = (const float4*)W;
        float4* Wd = (float4*)(&Ws[0][0]);
#pragma unroll
        for (int i = 0; i < 8; ++i) Wd[t + 256 * i] = Wsrc[t + 256 * i];
    }
    {
        int r = t >> 5;
        int c = (t & 31) * 4;
#pragma unroll
        for (int i = 0; i < 8; ++i) {
            int rr = r + 8 * i;
            int grow = row0 + rr;
            float4 v = make_float4(0.f, 0.f, 0.f, 0.f);
            if (grow < N) v = *(const float4*)(x + (size_t)grow * IN_F + c);
            xs[rr][c] = v.x; xs[rr][c + 1] = v.y; xs[rr][c + 2] = v.z; xs[rr][c + 3] = v.w;
        }
    }
    __syncthreads();

    const int tx = t & 15, ty = t >> 4;
    float acc[4][4] = {};

#pragma unroll 2
    for (int kk = 0; kk < 32; ++kk) {
        float4 xv[4];
#pragma unroll
        for (int i = 0; i < 4; ++i) xv[i] = *(const float4*)&xs[4 * ty + i][4 * kk];
#pragma unroll
        for (int kc = 0; kc < 4; ++kc) {
            float4 wv = *(const float4*)&Ws[4 * kk + kc][4 * tx];
#pragma unroll
            for (int i = 0; i < 4; ++i) {
                float xe = (kc == 0) ? xv[i].x : (kc == 1) ? xv[i].y : (kc == 2) ? xv[i].z : xv[i].w;
                acc[i][0] = fmaf(xe, wv.x, acc[i][0]);
                acc[i][1] = fmaf(xe, wv.y, acc[i][1]);
                acc[i][2] = fmaf(xe, wv.z, acc[i][2]);
                acc[i][3] = fmaf(xe, wv.w, acc[i][3]);
            }
        }
    }

    float4 al4 = ((const float4*)a_l)[tx];
    float4 ar4 = ((const float4*)a_r)[tx];

#pragma unroll
    for (int i = 0; i < 4; ++i) {
        int grow = row0 + 4 * ty + i;
        if (grow < N) {
            ushort4 o;
            o.x = f2bf(acc[i][0]); o.y = f2bf(acc[i][1]);
            o.z = f2bf(acc[i][2]); o.w = f2bf(acc[i][3]);
            *(ushort4*)(Whb + (size_t)grow * OUT_F + 4 * tx) = o;
        }
        float pl = acc[i][0] * al4.x + acc[i][1] * al4.y + acc[i][2] * al4.z + acc[i][3] * al4.w;
        float pr = acc[i][0] * ar4.x + acc[i][1] * ar4.y + acc[i][2] * ar4.z + acc[i][3] * ar4.w;
#pragma unroll
        for (int off = 1; off < 16; off <<= 1) {
            pl += __shfl_xor(pl, off);
            pr += __shfl_xor(pr, off);
        }
        if (tx == 0 && grow < N) { el[grow] = pl; er[grow] = pr; }
    }
}

// ------------- Binning stage A: per-block LDS histogram over coarse buckets
// hist2d layout: [bucket][NBLK]  (bucket-major, rows of NBLK for coalesced row reads)
__global__ void __launch_bounds__(256) countA(
    const int* __restrict__ src, int* __restrict__ hist2d, int E, int EPB, int NBUCK)
{
    extern __shared__ int h[];
    for (int i = threadIdx.x; i < NBUCK; i += 256) h[i] = 0;
    __syncthreads();
    const int b = blockIdx.x;
    const int e0 = b * EPB, e1 = min(e0 + EPB, E);
    for (int e = e0 + threadIdx.x; e < e1; e += 256)
        atomicAdd(&h[src[e] >> 6], 1);
    __syncthreads();
    for (int i = threadIdx.x; i < NBUCK; i += 256) hist2d[i * NBLK + b] = h[i];
}

// ------------- Stage B: bucket totals (wave per bucket, coalesced int4 row read)
__global__ void __launch_bounds__(256) sumB(
    const int* __restrict__ hist2d, int* __restrict__ total, int NBUCK)
{
    const int w = (blockIdx.x * blockDim.x + threadIdx.x) >> 6;
    const int lane = threadIdx.x & 63;
    if (w >= NBUCK) return;
    int4 v = ((const int4*)(hist2d + (size_t)w * NBLK))[lane];
    int s = v.x + v.y + v.z + v.w;
#pragma unroll
    for (int o = 32; o; o >>= 1) s += __shfl_xor(s, o);
    if (lane == 0) total[w] = s;
}

// ------------- Stage C: exclusive scan of bucket totals (single block)
__global__ void __launch_bounds__(256) scanS(
    const int* __restrict__ total, int* __restrict__ bbase, int* __restrict__ row_ptr,
    int NBUCK, int N, int E)
{
    __shared__ int wsum[4];
    const int t = threadIdx.x, lane = t & 63, wid = t >> 6;
    const int CH = (NBUCK + 255) / 256;   // ≤32 for N ≤ 524k
    int loc[32];
    int s = 0;
    for (int i = 0; i < CH && i < 32; ++i) {
        int idx = t * CH + i;
        int v = (idx < NBUCK) ? total[idx] : 0;
        loc[i] = v; s += v;
    }
    int incl = s;
#pragma unroll
    for (int o = 1; o < 64; o <<= 1) {
        int x = __shfl_up(incl, o);
        if (lane >= o) incl += x;
    }
    if (lane == 63) wsum[wid] = incl;
    __syncthreads();
    int wbase = 0;
    for (int k = 0; k < wid; ++k) wbase += wsum[k];
    int run = wbase + incl - s;
    for (int i = 0; i < CH && i < 32; ++i) {
        int idx = t * CH + i;
        if (idx < NBUCK) bbase[idx] = run;
        run += loc[i];
    }
    if (t == 0) { bbase[NBUCK] = E; row_ptr[N] = E; }
}

// ------------- Stage D: per-(block,bucket) offsets. offsets layout [block][NBUCK]
__global__ void __launch_bounds__(256) scanBB(
    const int* __restrict__ hist2d, const int* __restrict__ bbase,
    int* __restrict__ offsets, int NBUCK)
{
    const int w = (blockIdx.x * blockDim.x + threadIdx.x) >> 6;   // bucket
    const int lane = threadIdx.x & 63;
    if (w >= NBUCK) return;
    int4 v = ((const int4*)(hist2d + (size_t)w * NBLK))[lane];
    int s1 = v.x, s2 = s1 + v.y, s3 = s2 + v.z, s4 = s3 + v.w;
    int incl = s4;
#pragma unroll
    for (int o = 1; o < 64; o <<= 1) {
        int x = __shfl_up(incl, o);
        if (lane >= o) incl += x;
    }
    int base = bbase[w] + incl - s4;
    offsets[(size_t)(4 * lane + 0) * NBUCK + w] = base;
    offsets[(size_t)(4 * lane + 1) * NBUCK + w] = base + s1;
    offsets[(size_t)(4 * lane + 2) * NBUCK + w] = base + s2;
    offsets[(size_t)(4 * lane + 3) * NBUCK + w] = base + s3;
}

// ------------- Stage E: write packed records to bucket-grouped layout
__global__ void __launch_bounds__(256) binB(
    const int* __restrict__ src, const int* __restrict__ dst,
    const int* __restrict__ offsets, unsigned* __restrict__ rec,
    int E, int EPB, int NBUCK)
{
    extern __shared__ int sh[];           // [NBUCK offsets][NBUCK counters]
    int* off = sh;
    int* cnt = sh + NBUCK;
    const int b = blockIdx.x;
    for (int i = threadIdx.x; i < NBUCK; i += 256) {
        off[i] = offsets[(size_t)b * NBUCK + i];
        cnt[i] = 0;
    }
    __syncthreads();
    const int e0 = b * EPB, e1 = min(e0 + EPB, E);
    for (int e = e0 + threadIdx.x; e < e1; e += 256) {
        int s = src[e];
        int j = s >> 6;
        int r = atomicAdd(&cnt[j], 1);
        rec[off[j] + r] = ((unsigned)dst[e] << 6) | (unsigned)(s & 63);
    }
}

// ------------- Stage F: within-bucket fine bin; writes row_ptr, sdst, serv(=er[dst])
__global__ void __launch_bounds__(256) buckz(
    const unsigned* __restrict__ rec, const float* __restrict__ er,
    const int* __restrict__ bbase, int* __restrict__ row_ptr,
    int* __restrict__ sdst, float* __restrict__ serv, int N, int NBUCK)
{
    __shared__ unsigned recs[LCAP];
    __shared__ int cnt[64], cur[64];
    const int j = blockIdx.x;
    const int t = threadIdx.x;
    const int s0 = bbase[j], s1 = bbase[j + 1];
    const int len = s1 - s0;
    const bool lds = (len <= LCAP);

    if (t < 64) cnt[t] = 0;
    __syncthreads();
    for (int i = t; i < len; i += 256) {
        unsigned r = rec[s0 + i];
        if (lds) recs[i] = r;
        atomicAdd(&cnt[r & 63u], 1);
    }
    __syncthreads();
    if (t < 64) {
        int v = cnt[t];
        int incl = v;
#pragma unroll
        for (int o = 1; o < 64; o <<= 1) {
            int x = __shfl_up(incl, o);
            if (t >= o) incl += x;
        }
        cur[t] = incl - v;                       // exclusive
        int node = j * 64 + t;
        if (node < N) row_ptr[node] = s0 + incl - v;
    }
    __syncthreads();
    for (int i = t; i < len; i += 256) {
        unsigned r = lds ? recs[i] : rec[s0 + i];
        int s6 = (int)(r & 63u);
        int d  = (int)(r >> 6);
        int p  = atomicAdd(&cur[s6], 1);
        sdst[s0 + p] = d;
        serv[s0 + p] = er[d];
    }
}

// ---------------- node kernel: softmax + bf16 gather-aggregate + relu ------
__global__ void __launch_bounds__(256) node_k(
    const int* __restrict__ row_ptr, const int* __restrict__ sdst,
    const float* __restrict__ serv, const float* __restrict__ el,
    const unsigned short* __restrict__ Whb, float* __restrict__ out, int N)
{
    const int lane = threadIdx.x & 63;
    const int node = (blockIdx.x * blockDim.x + threadIdx.x) >> 6;
    if (node >= N) return;

    const int start = row_ptr[node], end = row_ptr[node + 1];
    const float elc = el[node];

    float m = -1e30f;
    for (int base = start; base < end; base += 64) {
        int idx = base + lane;
        if (idx < end) {
            float v = elc + serv[idx];
            v = v > 0.f ? v : NEG_SLOPE * v;
            m = fmaxf(m, v);
        }
    }
#pragma unroll
    for (int off = 32; off; off >>= 1) m = fmaxf(m, __shfl_xor(m, off));

    float Z = 0.f, acc = 0.f;
    for (int base = start; base < end; base += 64) {
        int idx = base + lane;
        int cnt = min(64, end - base);
        float p = 0.f;
        int d = 0;
        if (idx < end) {
            d = sdst[idx];
            float v = elc + serv[idx];
            v = v > 0.f ? v : NEG_SLOPE * v;
            p = __expf(v - m);
        }
        Z += p;
        for (int jj = 0; jj < cnt; ++jj) {
            int dj = __shfl(d, jj);
            float pj = __shfl(p, jj);
            acc = fmaf(pj, bf2f(Whb[(size_t)dj * OUT_F + lane]), acc);
        }
    }
#pragma unroll
    for (int off = 32; off; off >>= 1) Z += __shfl_xor(Z, off);

    out[(size_t)node * OUT_F + lane] = fmaxf(acc / (Z + 1e-9f), 0.f);
}

// ---------------------------------------------------------------------------
extern "C" void kernel_launch(void* const* d_in, const int* in_sizes, int n_in,
                              void* d_out, int out_size, void* d_ws, size_t ws_size,
                              hipStream_t stream)
{
    const float* x   = (const float*)d_in[0];
    const float* W   = (const float*)d_in[1];
    const float* a_l = (const float*)d_in[2];
    const float* a_r = (const float*)d_in[3];
    const int*   ei  = (const int*)d_in[4];

    const int N = in_sizes[0] / IN_F;
    const int E = in_sizes[4] / 2;
    const int* src = ei;
    const int* dst = ei + E;
    float* out = (float*)d_out;

    const int NBUCK = (N + 63) >> 6;
    const int EPB = (E + NBLK - 1) / NBLK;

    auto align = [](size_t v) { return (v + 255) & ~(size_t)255; };
    char* ws = (char*)d_ws;
    size_t off = 0;
    unsigned short* Whb = (unsigned short*)(ws + off); off = align(off + (size_t)N * OUT_F * 2);
    float* el      = (float*)(ws + off);   off = align(off + (size_t)N * 4);
    float* er      = (float*)(ws + off);   off = align(off + (size_t)N * 4);
    unsigned* rec  = (unsigned*)(ws + off);off = align(off + (size_t)E * 4);
    int* hist2d    = (int*)(ws + off);     off = align(off + (size_t)NBUCK * NBLK * 4);
    int* offsets   = (int*)(ws + off);     off = align(off + (size_t)NBUCK * NBLK * 4);
    int* total     = (int*)(ws + off);     off = align(off + (size_t)NBUCK * 4);
    int* bbase     = (int*)(ws + off);     off = align(off + (size_t)(NBUCK + 1) * 4);
    int* row_ptr   = (int*)(ws + off);     off = align(off + (size_t)(N + 1) * 4);
    int* sdst      = (int*)(ws + off);     off = align(off + (size_t)E * 4);
    float* serv    = (float*)(ws + off);   off = align(off + (size_t)E * 4);

    // 1. GEMM (produces Whb, el, er)
    gemm_tiled<<<(N + 63) / 64, 256, 0, stream>>>(x, W, a_l, a_r, Whb, el, er, N);

    // 2. binning chain (no global atomics, coalesced/windowed writes)
    countA<<<NBLK, 256, NBUCK * 4, stream>>>(src, hist2d, E, EPB, NBUCK);
    sumB  <<<(NBUCK + 3) / 4, 256, 0, stream>>>(hist2d, total, NBUCK);
    scanS <<<1, 256, 0, stream>>>(total, bbase, row_ptr, NBUCK, N, E);
    scanBB<<<(NBUCK + 3) / 4, 256, 0, stream>>>(hist2d, bbase, offsets, NBUCK);
    binB  <<<NBLK, 256, (size_t)NBUCK * 8, stream>>>(src, dst, offsets, rec, E, EPB, NBUCK);
    buckz <<<NBUCK, 256, 0, stream>>>(rec, er, bbase, row_ptr, sdst, serv, N, NBUCK);

    // 3. per-node softmax + aggregate + relu
    node_k<<<(N * 64 + 255) / 256, 256, 0, stream>>>(row_ptr, sdst, serv, el, Whb, out, N);
}